// Round 13
// baseline (208.526 us; speedup 1.0000x reference)
//
#include <hip/hip_runtime.h>
#include <stdint.h>

typedef __bf16 bf16x8_t __attribute__((ext_vector_type(8)));
typedef float f32x4_t __attribute__((ext_vector_type(4)));

#define AS1 __attribute__((address_space(1)))
#define AS3 __attribute__((address_space(3)))

static __device__ __forceinline__ unsigned short f2bf(float f) {
  union { float f; unsigned u; } a;
  a.f = f;
  unsigned r = a.u + 0x7fffu + ((a.u >> 16) & 1u);
  return (unsigned short)(r >> 16);
}

// HW packed f32x2 -> bf16x2 (RNE)
static __device__ __forceinline__ unsigned cvtpk(float lo, float hi) {
  unsigned r;
  asm("v_cvt_pk_bf16_f32 %0, %1, %2" : "=v"(r) : "v"(lo), "v"(hi));
  return r;
}

// ---------- 0. packed {cos,sin} table ----------
__global__ void build_cs(const float* __restrict__ sinp, const float* __restrict__ cosp,
                         float2* __restrict__ cs) {
  const int i = blockIdx.x * 256 + threadIdx.x;
  float2 v;
  v.x = cosp[i];
  v.y = sinp[i];
  cs[i] = v;
}

// ---------- 1. fp32 -> bf16 elementwise ----------
__global__ void cvt_bf16_kernel(const float* __restrict__ in, unsigned short* __restrict__ out) {
  long i = ((long)blockIdx.x * blockDim.x + threadIdx.x) * 4;
  float4 v = *(const float4*)(in + i);
  ushort4 o;
  o.x = f2bf(v.x);
  o.y = f2bf(v.y);
  o.z = f2bf(v.z);
  o.w = f2bf(v.w);
  *(ushort4*)(out + i) = o;
}

// ---------- 2. fp32 [R][C] (row stride ld) -> bf16 [C][R] ----------
__global__ void transpose_f32_bf16(const float* __restrict__ src, unsigned short* __restrict__ dst,
                                   int ld, int dld, long sbs, long dbs) {
  __shared__ float tile[64][65];
  src += (long)blockIdx.z * sbs;
  dst += (long)blockIdx.z * dbs;
  const int c0 = blockIdx.x * 64, r0 = blockIdx.y * 64;
  const int tx = threadIdx.x, ty = threadIdx.y;
#pragma unroll
  for (int j = 0; j < 64; j += 4)
    tile[ty + j][tx] = src[(long)(r0 + ty + j) * ld + (c0 + tx)];
  __syncthreads();
#pragma unroll
  for (int j = 0; j < 64; j += 4)
    dst[(long)(c0 + ty + j) * dld + (r0 + tx)] = f2bf(tile[tx][ty + j]);
}

#define STAGE_G(Abase, Bbase, buf, kt)                                                \
  {                                                                                   \
    _Pragma("unroll") for (int i = 0; i < 2; i++) {                                   \
      const int chunk = (i * 4 + wid) * 64 + lane;                                    \
      const int row = chunk >> 2;                                                     \
      __builtin_amdgcn_global_load_lds(                                               \
          (const AS1 void*)(A + (bm + row) * K + (kt) + sslot * 8),                   \
          (AS3 void*)(Abase + buf * 4096 + chunk * 8), 16, 0, 0);                     \
      __builtin_amdgcn_global_load_lds(                                               \
          (const AS1 void*)(Bt + (bn + row) * K + (kt) + sslot * 8),                  \
          (AS3 void*)(Bbase + buf * 4096 + chunk * 8), 16, 0, 0);                     \
    }                                                                                 \
  }

// ---------- 3. GEMM (r9 pipeline: 3-buf LDS, counted vmcnt, slot swizzle) ----------
__global__ __launch_bounds__(256) void gemm_bt(const unsigned short* __restrict__ A,
                                               const unsigned short* __restrict__ Bt,
                                               float* __restrict__ C,
                                               int M, int N, int K, int nx) {
  __shared__ unsigned short As[3][128 * 32];
  __shared__ unsigned short Bs[3][128 * 32];
  const int nwg = gridDim.x;
  const int bid = blockIdx.x;
  const int swz = (bid & 7) * (nwg >> 3) + (bid >> 3);
  const int by = swz / nx;
  const int bx = swz - by * nx;

  const int tid = threadIdx.x;
  const int wid = tid >> 6, lane = tid & 63;
  const int r16 = lane & 15, g = lane >> 4;
  const long bm = (long)by * 128;
  const long bn = (long)bx * 128;
  const int wr = (wid >> 1) * 64, wc = (wid & 1) * 64;
  const int gr = g ^ (r16 & 3);
  const int sslot = (lane & 3) ^ ((lane >> 2) & 3);

  f32x4_t acc[4][4];
#pragma unroll
  for (int i = 0; i < 4; i++)
#pragma unroll
    for (int j = 0; j < 4; j++) acc[i][j] = (f32x4_t){0.f, 0.f, 0.f, 0.f};

  const int NT = K >> 5;
  unsigned short* Ab = &As[0][0];
  unsigned short* Bb = &Bs[0][0];

  STAGE_G(Ab, Bb, 0, 0)
  STAGE_G(Ab, Bb, 1, 32)
  asm volatile("s_waitcnt vmcnt(4)" ::: "memory");
  __builtin_amdgcn_s_barrier();

  for (int T = 0; T < NT; T++) {
    const int cur = T % 3;
    if (T + 2 < NT) {
      const int nb = (T + 2) % 3;
      STAGE_G(Ab, Bb, nb, (T + 2) * 32)
    }
    __builtin_amdgcn_sched_barrier(0);
    bf16x8_t af[4], bfr[4];
#pragma unroll
    for (int mi = 0; mi < 4; mi++)
      af[mi] = *(const bf16x8_t*)(Ab + cur * 4096 + (wr + mi * 16 + r16) * 32 + gr * 8);
#pragma unroll
    for (int ni = 0; ni < 4; ni++)
      bfr[ni] = *(const bf16x8_t*)(Bb + cur * 4096 + (wc + ni * 16 + r16) * 32 + gr * 8);
    __builtin_amdgcn_s_setprio(1);
#pragma unroll
    for (int mi = 0; mi < 4; mi++)
#pragma unroll
      for (int ni = 0; ni < 4; ni++)
        acc[mi][ni] = __builtin_amdgcn_mfma_f32_16x16x32_bf16(af[mi], bfr[ni], acc[mi][ni], 0, 0, 0);
    __builtin_amdgcn_s_setprio(0);
    if (T + 2 < NT)
      asm volatile("s_waitcnt vmcnt(4)" ::: "memory");
    else
      asm volatile("s_waitcnt vmcnt(0)" ::: "memory");
    __builtin_amdgcn_s_barrier();
  }

#pragma unroll
  for (int mi = 0; mi < 4; mi++)
#pragma unroll
    for (int ni = 0; ni < 4; ni++) {
      const long rowb = bm + wr + mi * 16 + 4 * g;
      const long colb = bn + wc + ni * 16 + r16;
#pragma unroll
      for (int j = 0; j < 4; j++)
        C[(rowb + j) * N + colb] = acc[mi][ni][j];
    }
}

// ---------- 3b. GEMM1 fused: x @ Wqkv with RoPE + layout epilogue ----------
// N-tile 128 == one logical unit (tile 0..15 = q-head, 16 = k, 17 = v).
// Wave B-cols remapped to {wc'+0,16,64,80} (wc' in {0,32}) so lane holds both
// x[d] and x[d^64] (fragments ni, ni^2) -> RoPE fully in-register. Output via
// LDS (free after K-loop) for coalesced bf16 stores; v stored transposed.
// Writes qr (scaled 1/128*log2e), kr, vT directly — no fp32 qkv, no rope pass.
__global__ __launch_bounds__(256) void gemm_qkv_rope(
    const unsigned short* __restrict__ A,   // xb [4096][2048]
    const unsigned short* __restrict__ Bt,  // wqkvT [2304][2048]
    const float2* __restrict__ cs,          // [2048][128] {cos,sin}
    unsigned short* __restrict__ qr,
    unsigned short* __restrict__ kr,
    unsigned short* __restrict__ vT) {
  __shared__ unsigned short smem[6][128 * 32];  // 48KB: K-loop bufs; epilogue 128x136 tile
  const int K = 2048, nx = 18, nwg = 576;
  const int bid = blockIdx.x;
  const int swz = (bid & 7) * (nwg >> 3) + (bid >> 3);
  const int by = swz / nx;
  const int bx = swz - by * nx;

  const int tid = threadIdx.x;
  const int wid = tid >> 6, lane = tid & 63;
  const int r16 = lane & 15, g = lane >> 4;
  const long bm = (long)by * 128;
  const long bn = (long)bx * 128;
  const int wr = (wid >> 1) * 64;
  const int wcp = (wid & 1) * 32;  // remapped: cols wcp + {0,16,64,80} + r16
  const int gr = g ^ (r16 & 3);
  const int sslot = (lane & 3) ^ ((lane >> 2) & 3);
  const int colmap[4] = {0, 16, 64, 80};

  f32x4_t acc[4][4];
#pragma unroll
  for (int i = 0; i < 4; i++)
#pragma unroll
    for (int j = 0; j < 4; j++) acc[i][j] = (f32x4_t){0.f, 0.f, 0.f, 0.f};

  const int NT = K >> 5;  // 64
  unsigned short* Ab = &smem[0][0];
  unsigned short* Bb = &smem[3][0];

  STAGE_G(Ab, Bb, 0, 0)
  STAGE_G(Ab, Bb, 1, 32)
  asm volatile("s_waitcnt vmcnt(4)" ::: "memory");
  __builtin_amdgcn_s_barrier();

  for (int T = 0; T < NT; T++) {
    const int cur = T % 3;
    if (T + 2 < NT) {
      const int nb = (T + 2) % 3;
      STAGE_G(Ab, Bb, nb, (T + 2) * 32)
    }
    __builtin_amdgcn_sched_barrier(0);
    bf16x8_t af[4], bfr[4];
#pragma unroll
    for (int mi = 0; mi < 4; mi++)
      af[mi] = *(const bf16x8_t*)(Ab + cur * 4096 + (wr + mi * 16 + r16) * 32 + gr * 8);
#pragma unroll
    for (int ni = 0; ni < 4; ni++)
      bfr[ni] = *(const bf16x8_t*)(Bb + cur * 4096 + (wcp + colmap[ni] + r16) * 32 + gr * 8);
    __builtin_amdgcn_s_setprio(1);
#pragma unroll
    for (int mi = 0; mi < 4; mi++)
#pragma unroll
      for (int ni = 0; ni < 4; ni++)
        acc[mi][ni] = __builtin_amdgcn_mfma_f32_16x16x32_bf16(af[mi], bfr[ni], acc[mi][ni], 0, 0, 0);
    __builtin_amdgcn_s_setprio(0);
    if (T + 2 < NT)
      asm volatile("s_waitcnt vmcnt(4)" ::: "memory");
    else
      asm volatile("s_waitcnt vmcnt(0)" ::: "memory");
    __builtin_amdgcn_s_barrier();
  }
  // ---- fused epilogue (last loop iter ended with a full barrier: smem free) ----
  const int b = by >> 4;            // token batch
  const int tseq0 = (by & 15) * 128;  // t within sequence
  unsigned short* sm = &smem[0][0];   // 128 x 136 bf16 tile (34.8KB of 48)

  if (bx < 17) {  // q-head (bx) or k (bx==16): RoPE
    const bool isq = (bx < 16);
#pragma unroll
    for (int mi = 0; mi < 4; mi++) {
#pragma unroll
      for (int ni = 0; ni < 4; ni++) {
        const int d = wcp + colmap[ni] + r16;
        const float sgn = (ni < 2) ? -1.f : 1.f;  // d<64 <=> ni<2
#pragma unroll
        for (int j = 0; j < 4; j++) {
          const int tl = wr + mi * 16 + 4 * g + j;
          const float2 c = cs[(long)(tseq0 + tl) * 128 + d];
          float v = acc[mi][ni][j] * c.x + sgn * acc[mi][ni ^ 2][j] * c.y;
          if (isq) v *= 0.011271055f;  // 1/128 * log2(e): exp2-domain softmax
          sm[tl * 136 + d] = f2bf(v);
        }
      }
    }
    __syncthreads();
    const int trow = tid >> 1, half = (tid & 1) * 64;
    unsigned short* dst =
        isq ? (qr + ((long)(b * 16 + bx) * 2048 + tseq0) * 128)
            : (kr + ((long)b * 2048 + tseq0) * 128);
    dst += (long)trow * 128 + half;
#pragma unroll
    for (int i = 0; i < 8; i++)
      *(bf16x8_t*)(dst + i * 8) = *(const bf16x8_t*)(sm + trow * 136 + half + i * 8);
  } else {  // v: plain cvt, stored transposed [d][t]
#pragma unroll
    for (int mi = 0; mi < 4; mi++)
#pragma unroll
      for (int ni = 0; ni < 4; ni++) {
        const int d = wcp + colmap[ni] + r16;
#pragma unroll
        for (int j = 0; j < 4; j++) {
          const int tl = wr + mi * 16 + 4 * g + j;
          sm[d * 136 + tl] = f2bf(acc[mi][ni][j]);
        }
      }
    __syncthreads();
    const int drow = tid >> 1, half = (tid & 1) * 64;
    unsigned short* dst = vT + (long)b * 128 * 2048 + (long)drow * 2048 + tseq0 + half;
#pragma unroll
    for (int i = 0; i < 8; i++)
      *(bf16x8_t*)(dst + i * 8) = *(const bf16x8_t*)(sm + drow * 136 + half + i * 8);
  }
}

// ---------- 5. causal MQA flash attention (v10, unchanged from round 12) ----------
__global__ __launch_bounds__(256, 2)
void mqa_attn(const unsigned short* __restrict__ qr,
              const unsigned short* __restrict__ kr,
              const unsigned short* __restrict__ vT,
              unsigned short* __restrict__ ao) {
  __shared__ unsigned short Kb[2][64 * 128];
  __shared__ unsigned short Vb[2][128 * 64];
  __shared__ unsigned short plds[4][16 * 64];
  const int idx = blockIdx.x;
  const int pj = idx & 15, h = (idx >> 4) & 15, b = idx >> 8;
  const int tid = threadIdx.x;
  const int wid = tid >> 6, lane = tid & 63;
  const int r = lane & 15, g = lane >> 4;
  const int rs = r & 7;
  char* pw = (char*)&plds[wid][0];

  const unsigned short* kbase = kr + (long)b * 2048 * 128;
  const unsigned short* vbase = vT + (long)b * 128 * 2048;
  const unsigned short* qh = qr + (long)(b * 16 + h) * 2048 * 128;

  const int scol = (tid & 15) ^ ((tid >> 4) & 7);
  const int vscol = (tid & 7) ^ ((tid >> 3) & 7);

  f32x4_t o[8];
#pragma unroll
  for (int i = 0; i < 8; i++) o[i] = (f32x4_t){0.f, 0.f, 0.f, 0.f};
  float m = 0.f, lsum = 0.f;

  int tile = pj;
  bf16x8_t qf[4];
  {
    const unsigned short* qp = qh + (long)(tile * 64 + wid * 16 + r) * 128 + g * 8;
#pragma unroll
    for (int c = 0; c < 4; c++) qf[c] = *(const bf16x8_t*)(qp + c * 32);
  }

#pragma unroll
  for (int i = 0; i < 4; i++) {
    const int row = i * 16 + (tid >> 4);
    __builtin_amdgcn_global_load_lds(
        (const AS1 void*)(kbase + (long)row * 128 + scol * 8),
        (AS3 void*)(&Kb[0][(i * 256 + tid) * 8]), 16, 0, 0);
  }
#pragma unroll
  for (int i = 0; i < 4; i++) {
    const int vrow = i * 32 + (tid >> 3);
    __builtin_amdgcn_global_load_lds(
        (const AS1 void*)(vbase + (long)vrow * 2048 + vscol * 8),
        (AS3 void*)(&Vb[0][(i * 256 + tid) * 8]), 16, 0, 0);
  }
  asm volatile("s_waitcnt vmcnt(0)" ::: "memory");
  __builtin_amdgcn_s_barrier();

  const int switch_s = pj + 1;
  for (int s = 0; s <= 32; s++) {
    const int cur = s & 1;

    if (s == switch_s) {
      float lt = lsum;
      lt += __shfl_xor(lt, 16);
      lt += __shfl_xor(lt, 32);
      float rl[4];
#pragma unroll
      for (int jj = 0; jj < 4; jj++) rl[jj] = 1.0f / __shfl(lt, 4 * g + jj);
      unsigned short* aop = ao + ((long)(b * 2048 + tile * 64 + wid * 16 + 4 * g)) * 2048 + h * 128 + r;
#pragma unroll
      for (int dt = 0; dt < 8; dt++)
#pragma unroll
        for (int jj = 0; jj < 4; jj++)
          aop[(long)jj * 2048 + dt * 16] = f2bf(o[dt][jj] * rl[jj]);
      tile = 31 - pj;
      const unsigned short* qp = qh + (long)(tile * 64 + wid * 16 + r) * 128 + g * 8;
#pragma unroll
      for (int c = 0; c < 4; c++) qf[c] = *(const bf16x8_t*)(qp + c * 32);
#pragma unroll
      for (int i = 0; i < 8; i++) o[i] = (f32x4_t){0.f, 0.f, 0.f, 0.f};
      m = 0.f;
      lsum = 0.f;
    }

    if (s < 32) {
      const int kvn = (s + 1 <= pj) ? 64 * (s + 1) : 64 * (s - pj);
#pragma unroll
      for (int i = 0; i < 4; i++) {
        const int row = i * 16 + (tid >> 4);
        __builtin_amdgcn_global_load_lds(
            (const AS1 void*)(kbase + (long)(kvn + row) * 128 + scol * 8),
            (AS3 void*)(&Kb[cur ^ 1][(i * 256 + tid) * 8]), 16, 0, 0);
      }
      __builtin_amdgcn_sched_barrier(0);
#pragma unroll
      for (int i = 0; i < 4; i++) {
        const int vrow = i * 32 + (tid >> 3);
        __builtin_amdgcn_global_load_lds(
            (const AS1 void*)(vbase + (long)vrow * 2048 + kvn + vscol * 8),
            (AS3 void*)(&Vb[cur ^ 1][(i * 256 + tid) * 8]), 16, 0, 0);
      }
    }
    __builtin_amdgcn_sched_barrier(0);

    f32x4_t sc[4];
#pragma unroll
    for (int t = 0; t < 4; t++) sc[t] = (f32x4_t){0.f, 0.f, 0.f, 0.f};
    const unsigned short* Kcur = &Kb[cur][0];
    __builtin_amdgcn_s_setprio(1);
#pragma unroll
    for (int t = 0; t < 4; t++) {
      const unsigned short* krow = Kcur + (16 * t + r) * 128;
#pragma unroll
      for (int c = 0; c < 4; c++) {
        const bf16x8_t kf = *(const bf16x8_t*)(krow + (((4 * c + g) ^ rs) << 3));
        sc[t] = __builtin_amdgcn_mfma_f32_16x16x32_bf16(kf, qf[c], sc[t], 0, 0, 0);
      }
    }
    __builtin_amdgcn_s_setprio(0);

    if (s == pj || s == 32) {
#pragma unroll
      for (int t = 0; t < 4; t++)
#pragma unroll
        for (int jj = 0; jj < 4; jj++)
          if (t * 16 + 4 * g + jj > wid * 16 + r) sc[t][jj] = -1e30f;
    }
    float mx01 = fmaxf(fmaxf(sc[0][0], sc[0][1]), fmaxf(sc[0][2], sc[0][3]));
    float mx23 = fmaxf(fmaxf(sc[1][0], sc[1][1]), fmaxf(sc[1][2], sc[1][3]));
    float mx45 = fmaxf(fmaxf(sc[2][0], sc[2][1]), fmaxf(sc[2][2], sc[2][3]));
    float mx67 = fmaxf(fmaxf(sc[3][0], sc[3][1]), fmaxf(sc[3][2], sc[3][3]));
    const float lm = fmaxf(fmaxf(mx01, mx23), fmaxf(mx45, mx67));
    if (!__all(lm <= m + 11.5f)) {
      float pm = lm;
      pm = fmaxf(pm, __shfl_xor(pm, 16));
      pm = fmaxf(pm, __shfl_xor(pm, 32));
      const float mnew = fmaxf(m, pm);
      const float alpha = __builtin_amdgcn_exp2f(m - mnew);
      lsum *= alpha;
      float aj[4];
#pragma unroll
      for (int jj = 0; jj < 4; jj++) aj[jj] = __shfl(alpha, 4 * g + jj);
#pragma unroll
      for (int dt = 0; dt < 8; dt++) {
        o[dt][0] *= aj[0]; o[dt][1] *= aj[1]; o[dt][2] *= aj[2]; o[dt][3] *= aj[3];
      }
      m = mnew;
    }
    float p[16];
#pragma unroll
    for (int t = 0; t < 4; t++)
#pragma unroll
      for (int jj = 0; jj < 4; jj++) p[4 * t + jj] = __builtin_amdgcn_exp2f(sc[t][jj] - m);
    float ls = 0.f;
#pragma unroll
    for (int i = 0; i < 16; i++) ls += p[i];
    lsum += ls;

    asm volatile("" ::: "memory");
#pragma unroll
    for (int t = 0; t < 4; t++) {
      uint2 w = {cvtpk(p[4 * t], p[4 * t + 1]), cvtpk(p[4 * t + 2], p[4 * t + 3])};
      *(uint2*)(pw + r * 128 + (((2 * t + (g >> 1)) ^ rs) << 4) + ((g & 1) << 3)) = w;
    }
    asm volatile("s_waitcnt lgkmcnt(0)" ::: "memory");
    const bf16x8_t pa0 = *(const bf16x8_t*)(pw + r * 128 + ((g ^ rs) << 4));
    const bf16x8_t pa1 = *(const bf16x8_t*)(pw + r * 128 + (((4 + g) ^ rs) << 4));

    if (s < 32)
      asm volatile("s_waitcnt vmcnt(8)" ::: "memory");
    else
      asm volatile("s_waitcnt vmcnt(0)" ::: "memory");
    __builtin_amdgcn_s_barrier();

    const unsigned short* Vcur = &Vb[cur][0];
    __builtin_amdgcn_s_setprio(1);
#pragma unroll
    for (int dt = 0; dt < 8; dt++) {
      const bf16x8_t vfA = *(const bf16x8_t*)(Vcur + (dt * 16 + r) * 64 + ((g ^ rs) << 3));
      o[dt] = __builtin_amdgcn_mfma_f32_16x16x32_bf16(pa0, vfA, o[dt], 0, 0, 0);
    }
#pragma unroll
    for (int dt = 0; dt < 8; dt++) {
      const bf16x8_t vfB = *(const bf16x8_t*)(Vcur + (dt * 16 + r) * 64 + (((4 + g) ^ rs) << 3));
      o[dt] = __builtin_amdgcn_mfma_f32_16x16x32_bf16(pa1, vfB, o[dt], 0, 0, 0);
    }
    __builtin_amdgcn_s_setprio(0);

    if (s < 32)
      asm volatile("s_waitcnt vmcnt(4)" ::: "memory");
    else
      asm volatile("s_waitcnt vmcnt(0)" ::: "memory");
    __builtin_amdgcn_s_barrier();
  }
  {
    float lt = lsum;
    lt += __shfl_xor(lt, 16);
    lt += __shfl_xor(lt, 32);
    float rl[4];
#pragma unroll
    for (int jj = 0; jj < 4; jj++) rl[jj] = 1.0f / __shfl(lt, 4 * g + jj);
    unsigned short* aop = ao + ((long)(b * 2048 + tile * 64 + wid * 16 + 4 * g)) * 2048 + h * 128 + r;
#pragma unroll
    for (int dt = 0; dt < 8; dt++)
#pragma unroll
      for (int jj = 0; jj < 4; jj++)
        aop[(long)jj * 2048 + dt * 16] = f2bf(o[dt][jj] * rl[jj]);
  }
}

extern "C" void kernel_launch(void* const* d_in, const int* in_sizes, int n_in,
                              void* d_out, int out_size, void* d_ws, size_t ws_size,
                              hipStream_t stream) {
  const float* x    = (const float*)d_in[0];
  const float* sinp = (const float*)d_in[1];
  const float* cosp = (const float*)d_in[2];
  const float* Wqkv = (const float*)d_in[3];
  const float* Wo   = (const float*)d_in[4];
  float* out = (float*)d_out;
  char* ws = (char*)d_ws;

  const int B = 2, T = 2048, D = 2048, H = 16, HD = 128;
  const int M = B * T;        // 4096
  const int NQ = D + 2 * HD;  // 2304

  unsigned short* xb    = (unsigned short*)(ws + 0);         // 16,777,216
  unsigned short* wqkvT = (unsigned short*)(ws + 16777216);  //  9,437,184
  unsigned short* woT   = (unsigned short*)(ws + 26214400);  //  8,388,608
  float2*         cstab = (float2*)        (ws + 34603008);  //  2,097,152
  unsigned short* qr    = (unsigned short*)(ws + 36700160);  // 16,777,216
  unsigned short* kr    = (unsigned short*)(ws + 53477376);  //  1,048,576
  unsigned short* vT    = (unsigned short*)(ws + 54525952);  //  1,048,576
  unsigned short* ao    = xb;  // reuse xb after GEMM1

  dim3 tb(64, 4);
  build_cs<<<(T * HD) / 256, 256, 0, stream>>>(sinp, cosp, cstab);
  cvt_bf16_kernel<<<(M * D) / 1024, 256, 0, stream>>>(x, xb);
  transpose_f32_bf16<<<dim3(NQ / 64, D / 64, 1), tb, 0, stream>>>(Wqkv, wqkvT, NQ, D, 0, 0);
  transpose_f32_bf16<<<dim3(D / 64, D / 64, 1), tb, 0, stream>>>(Wo, woT, D, D, 0, 0);
  gemm_qkv_rope<<<dim3((NQ / 128) * (M / 128)), 256, 0, stream>>>(xb, wqkvT, cstab, qr, kr, vT);
  mqa_attn<<<dim3(512), 256, 0, stream>>>(qr, kr, vT, ao);
  gemm_bt<<<dim3((D / 128) * (M / 128)), 256, 0, stream>>>(ao, woT, out, M, D, D, D / 128);
}